// Round 14
// baseline (384.983 us; speedup 1.0000x reference)
//
#include <hip/hip_runtime.h>
#include <math.h>

// Problem constants
constexpr int kB  = 2048;
constexpr int kNG = 20000;
constexpr int kP  = 256;
constexpr int kG  = 64;
constexpr int kE  = 128;
constexpr int kT  = 32;
constexpr int kNPG = 32;   // number of pathway groups
constexpr int kPPG = 8;    // pathways per group
constexpr int kBT  = 64;   // batch tile
constexpr int kNBT = kB / kBT;   // 32

// ---------------------------------------------------------------------------
// T0: transpose x_genes [B][NG] f32 -> xgT [NG][B] f32 (exact).
// float4 global loads/stores; LDS hops scalar at stride 65 (2-way = free).
// ---------------------------------------------------------------------------
__global__ __launch_bounds__(256) void k_transpose(
    const float* __restrict__ xg, float* __restrict__ xgT)
{
    __shared__ float t[64][65];
    const int g0 = blockIdx.x * 64, b0 = blockIdx.y * 64;
    const int tid = threadIdx.x;
    const bool tail = (g0 + 64 > kNG);

    const int gi = tid & 15;   // float4 column index
    const int br = tid >> 4;   // base row
#pragma unroll
    for (int it = 0; it < 4; ++it) {
        const int b = br + 16 * it;
        const int g = g0 + gi * 4;
        float4 v;
        if (!tail) {
            v = *(const float4*)&xg[(size_t)(b0 + b) * kNG + g];
        } else {
            v.x = (g + 0 < kNG) ? xg[(size_t)(b0 + b) * kNG + g + 0] : 0.f;
            v.y = (g + 1 < kNG) ? xg[(size_t)(b0 + b) * kNG + g + 1] : 0.f;
            v.z = (g + 2 < kNG) ? xg[(size_t)(b0 + b) * kNG + g + 2] : 0.f;
            v.w = (g + 3 < kNG) ? xg[(size_t)(b0 + b) * kNG + g + 3] : 0.f;
        }
        t[b][gi * 4 + 0] = v.x;
        t[b][gi * 4 + 1] = v.y;
        t[b][gi * 4 + 2] = v.z;
        t[b][gi * 4 + 3] = v.w;
    }
    __syncthreads();
    const int bi = tid & 15;
    const int gr = tid >> 4;
#pragma unroll
    for (int it = 0; it < 4; ++it) {
        const int g = gr + 16 * it;
        if (g0 + g < kNG) {
            float4 v;
            v.x = t[4 * bi + 0][g];
            v.y = t[4 * bi + 1][g];
            v.z = t[4 * bi + 2][g];
            v.w = t[4 * bi + 3][g];
            *(float4*)&xgT[(size_t)(g0 + g) * kB + b0 + 4 * bi] = v;
        }
    }
}

// XCD-aware flat-grid decode: 1024 blocks, 8 XCDs
static __device__ __forceinline__ void decode_swz64(int bid, int& p0, int& b0) {
    const int swz = ((bid & 7) << 7) | (bid >> 3);  // bijective, 1024%8==0
    p0 = (swz >> 5) * kPPG;
    b0 = (swz & 31) * kBT;
}

// ---------------------------------------------------------------------------
// k_tokens: R13 structure + T14 async-split gather (issue-early/write-late).
// Pathway pp+1's 16 gather loads are issued right after the first barrier
// and stay in flight across ~2560 cycles of FMA; regs written to xs at the
// top of the next iteration. No launch-bounds clamp (R5's spill trap: 84+16
// VGPR fits 128/wave for 4 blocks/CU). FMA order unchanged -> same bits.
// ---------------------------------------------------------------------------
__global__ __launch_bounds__(256) void k_tokens(
    const float* __restrict__ xgT, const int* __restrict__ pidx,
    const float* __restrict__ Wp, const float* __restrict__ bp,
    float* __restrict__ tok, float* __restrict__ pmean)
{
    __shared__ __align__(16) float wp[kG / 2][kE];  // 16 KB (half-K chunk)
    __shared__ __align__(16) float xs[kBT][66];     // 16.5 KB

    const int tid  = threadIdx.x;
    int p0, b0;
    decode_swz64(blockIdx.x, p0, b0);
    const int pg   = p0 / kPPG;
    const int e0   = (tid & 31) * 4;
    const int bq8  = (tid >> 5) * 8;
    const int lane = tid & 63;
    const int wv   = tid >> 6;

    float macc[8][4];
#pragma unroll
    for (int i = 0; i < 8; ++i)
#pragma unroll
        for (int j = 0; j < 4; ++j) macc[i][j] = 0.f;

    // prologue: issue gather for pathway p0 into registers
    float nv[16];
#pragma unroll
    for (int t = 0; t < 8; ++t) {
        const int gp = wv + 4 * t;
        const int c0 = pidx[p0 * kG + 2 * gp];
        const int c1 = pidx[p0 * kG + 2 * gp + 1];
        nv[2 * t]     = xgT[(size_t)c0 * kB + b0 + lane];
        nv[2 * t + 1] = xgT[(size_t)c1 * kB + b0 + lane];
    }

    for (int pp = 0; pp < kPPG; ++pp) {
        const int p = p0 + pp;
        // write prefetched gather into xs (write-late half of T14)
#pragma unroll
        for (int t = 0; t < 8; ++t) {
            const int gp = wv + 4 * t;
            *(float2*)&xs[lane][2 * gp] = make_float2(nv[2 * t], nv[2 * t + 1]);
        }
        // stage Wp half A (genes 0..31): 1024 float4 / 256 thr
        {
            const float4* wsrc = (const float4*)(Wp + (size_t)p * kG * kE);
            float4* wdst = (float4*)(&wp[0][0]);
#pragma unroll
            for (int it = 0; it < 4; ++it) wdst[it * 256 + tid] = wsrc[it * 256 + tid];
        }
        float bpr[4];
        {
            const float4 b4 = *(const float4*)&bp[p * kE + e0];
            bpr[0] = b4.x; bpr[1] = b4.y; bpr[2] = b4.z; bpr[3] = b4.w;
        }
        __syncthreads();

        // issue-early half of T14: next pathway's gathers overlap the FMAs
        if (pp + 1 < kPPG) {
            const int pn = p + 1;
#pragma unroll
            for (int t = 0; t < 8; ++t) {
                const int gp = wv + 4 * t;
                const int c0 = pidx[pn * kG + 2 * gp];
                const int c1 = pidx[pn * kG + 2 * gp + 1];
                nv[2 * t]     = xgT[(size_t)c0 * kB + b0 + lane];
                nv[2 * t + 1] = xgT[(size_t)c1 * kB + b0 + lane];
            }
        }

        float acc[8][4];
#pragma unroll
        for (int i = 0; i < 8; ++i)
#pragma unroll
            for (int j = 0; j < 4; ++j) acc[i][j] = 0.f;

#pragma unroll
        for (int half = 0; half < 2; ++half) {
            if (half == 1) {
                __syncthreads();  // all reads of half A done
                const float4* wsrc = (const float4*)(Wp + (size_t)p * kG * kE) + 1024;
                float4* wdst = (float4*)(&wp[0][0]);
#pragma unroll
                for (int it = 0; it < 4; ++it) wdst[it * 256 + tid] = wsrc[it * 256 + tid];
                __syncthreads();  // half B staged
            }
            const int xoff = half * 32;
#pragma unroll 4
            for (int gq = 0; gq < 8; ++gq) {
                const int g0 = gq * 4;
                float4 wrow[4];
#pragma unroll
                for (int k = 0; k < 4; ++k) wrow[k] = *(const float4*)&wp[g0 + k][e0];
#pragma unroll
                for (int i = 0; i < 8; ++i) {
                    const float2 xa01 = *(const float2*)&xs[bq8 + i][xoff + g0];
                    const float2 xa23 = *(const float2*)&xs[bq8 + i][xoff + g0 + 2];
                    const float xa[4] = {xa01.x, xa01.y, xa23.x, xa23.y};
#pragma unroll
                    for (int k = 0; k < 4; ++k) {
                        acc[i][0] = fmaf(xa[k], wrow[k].x, acc[i][0]);
                        acc[i][1] = fmaf(xa[k], wrow[k].y, acc[i][1]);
                        acc[i][2] = fmaf(xa[k], wrow[k].z, acc[i][2]);
                        acc[i][3] = fmaf(xa[k], wrow[k].w, acc[i][3]);
                    }
                }
            }
        }
        // relu + bias, store tokens, accumulate partial mean
#pragma unroll
        for (int i = 0; i < 8; ++i) {
            float4 r4;
            r4.x = fmaxf(acc[i][0] + bpr[0], 0.f);
            r4.y = fmaxf(acc[i][1] + bpr[1], 0.f);
            r4.z = fmaxf(acc[i][2] + bpr[2], 0.f);
            r4.w = fmaxf(acc[i][3] + bpr[3], 0.f);
            macc[i][0] += r4.x; macc[i][1] += r4.y;
            macc[i][2] += r4.z; macc[i][3] += r4.w;
            *(float4*)&tok[((size_t)p * kB + b0 + bq8 + i) * kE + e0] = r4;
        }
        __syncthreads();  // all xs/wp reads done -> next iter may overwrite
    }
    // non-atomic partial mean: (pg, b, e) owned by exactly one thread
#pragma unroll
    for (int i = 0; i < 8; ++i)
        *(float4*)&pmean[((size_t)pg * kB + b0 + bq8 + i) * kE + e0] =
            make_float4(macc[i][0], macc[i][1], macc[i][2], macc[i][3]);
}

// ---------------------------------------------------------------------------
// k_scoretok: scores + online softmax + partial ctx from stored tokens.
// ---------------------------------------------------------------------------
__global__ __launch_bounds__(256) void k_scoretok(
    const float* __restrict__ tok, const float* __restrict__ query,
    float* __restrict__ part_m, float* __restrict__ part_l,
    float* __restrict__ part_ctx)
{
    const int tid = threadIdx.x;
    const int b0  = blockIdx.x * kBT;
    const int pg  = blockIdx.y;
    const int eq  = tid & 31;
    const int e0  = eq * 4;
    const int bq8 = (tid >> 5) * 8;
    const float rsqE = 0.08838834764831845f; // 1/sqrt(128)

    float qreg[8][4];
#pragma unroll
    for (int i = 0; i < 8; ++i) {
        const float4 qv = *(const float4*)&query[(size_t)(b0 + bq8 + i) * kE + e0];
        qreg[i][0] = qv.x; qreg[i][1] = qv.y; qreg[i][2] = qv.z; qreg[i][3] = qv.w;
    }

    float m[8], l[8], ctx[8][4];
#pragma unroll
    for (int i = 0; i < 8; ++i) {
        m[i] = -1e30f; l[i] = 0.f;
#pragma unroll
        for (int j = 0; j < 4; ++j) ctx[i][j] = 0.f;
    }

    for (int pp = 0; pp < kPPG; ++pp) {
        const int p = pg * kPPG + pp;
#pragma unroll
        for (int i = 0; i < 8; ++i) {
            const float4 t4 = *(const float4*)&tok[((size_t)p * kB + b0 + bq8 + i) * kE + e0];
            float ps = t4.x * qreg[i][0] + t4.y * qreg[i][1]
                     + t4.z * qreg[i][2] + t4.w * qreg[i][3];
            ps += __shfl_xor(ps, 1);
            ps += __shfl_xor(ps, 2);
            ps += __shfl_xor(ps, 4);
            ps += __shfl_xor(ps, 8);
            ps += __shfl_xor(ps, 16);
            const float s  = ps * rsqE;
            const float mn = fmaxf(m[i], s);
            const float sc = __expf(m[i] - mn);
            const float w  = __expf(s - mn);
            l[i] = l[i] * sc + w;
            ctx[i][0] = ctx[i][0] * sc + w * t4.x;
            ctx[i][1] = ctx[i][1] * sc + w * t4.y;
            ctx[i][2] = ctx[i][2] * sc + w * t4.z;
            ctx[i][3] = ctx[i][3] * sc + w * t4.w;
            m[i] = mn;
        }
    }

    if (eq == 0) {
#pragma unroll
        for (int i = 0; i < 8; ++i) {
            part_m[(size_t)(b0 + bq8 + i) * kNPG + pg] = m[i];
            part_l[(size_t)(b0 + bq8 + i) * kNPG + pg] = l[i];
        }
    }
#pragma unroll
    for (int i = 0; i < 8; ++i)
#pragma unroll
        for (int j = 0; j < 4; ++j)
            part_ctx[((size_t)(b0 + bq8 + i) * kNPG + pg) * kE + e0 + j] = ctx[i][j];
}

// ---------------------------------------------------------------------------
// Fallback pass A/B (R7-proven BT=64 recompute path) — used if tok doesn't fit
// ---------------------------------------------------------------------------
__global__ __launch_bounds__(256) void k_meanpass(
    const float* __restrict__ xgT, const int* __restrict__ pidx,
    const float* __restrict__ Wp, const float* __restrict__ bp,
    float* __restrict__ meanSum)
{
    __shared__ __align__(16) float wp[kG][kE];
    __shared__ __align__(16) float xs[kBT][66];
    __shared__ float bps[kE];

    const int tid  = threadIdx.x;
    int p0, b0;
    decode_swz64(blockIdx.x, p0, b0);
    const int e0   = (tid & 31) * 4;
    const int bq8  = (tid >> 5) * 8;
    const int lane = tid & 63;
    const int wv   = tid >> 6;

    float macc[8][4];
#pragma unroll
    for (int i = 0; i < 8; ++i)
#pragma unroll
        for (int j = 0; j < 4; ++j) macc[i][j] = 0.f;

    for (int pp = 0; pp < kPPG; ++pp) {
        const int p = p0 + pp;
        const float4* wsrc = (const float4*)(Wp + (size_t)p * kG * kE);
        float4* wdst = (float4*)(&wp[0][0]);
#pragma unroll
        for (int it = 0; it < 8; ++it) wdst[it * 256 + tid] = wsrc[it * 256 + tid];
        if (tid < kE) bps[tid] = bp[p * kE + tid];
#pragma unroll
        for (int t = 0; t < 8; ++t) {
            const int gp = wv + 4 * t;
            const int c0 = pidx[p * kG + 2 * gp];
            const int c1 = pidx[p * kG + 2 * gp + 1];
            const float v0 = xgT[(size_t)c0 * kB + b0 + lane];
            const float v1 = xgT[(size_t)c1 * kB + b0 + lane];
            *(float2*)&xs[lane][2 * gp] = make_float2(v0, v1);
        }
        __syncthreads();

        float bpr[4];
#pragma unroll
        for (int j = 0; j < 4; ++j) bpr[j] = bps[e0 + j];

        float acc[8][4];
#pragma unroll
        for (int i = 0; i < 8; ++i)
#pragma unroll
            for (int j = 0; j < 4; ++j) acc[i][j] = 0.f;

#pragma unroll 4
        for (int gq = 0; gq < 16; ++gq) {
            const int g0 = gq * 4;
            float4 wrow[4];
#pragma unroll
            for (int k = 0; k < 4; ++k) wrow[k] = *(const float4*)&wp[g0 + k][e0];
#pragma unroll
            for (int i = 0; i < 8; ++i) {
                const float2 xa01 = *(const float2*)&xs[bq8 + i][g0];
                const float2 xa23 = *(const float2*)&xs[bq8 + i][g0 + 2];
                const float xa[4] = {xa01.x, xa01.y, xa23.x, xa23.y};
#pragma unroll
                for (int k = 0; k < 4; ++k) {
                    acc[i][0] = fmaf(xa[k], wrow[k].x, acc[i][0]);
                    acc[i][1] = fmaf(xa[k], wrow[k].y, acc[i][1]);
                    acc[i][2] = fmaf(xa[k], wrow[k].z, acc[i][2]);
                    acc[i][3] = fmaf(xa[k], wrow[k].w, acc[i][3]);
                }
            }
        }
#pragma unroll
        for (int i = 0; i < 8; ++i)
#pragma unroll
            for (int j = 0; j < 4; ++j)
                macc[i][j] += fmaxf(acc[i][j] + bpr[j], 0.f);
        __syncthreads();
    }
#pragma unroll
    for (int i = 0; i < 8; ++i)
#pragma unroll
        for (int j = 0; j < 4; ++j)
            atomicAdd(&meanSum[(size_t)(b0 + bq8 + i) * kE + e0 + j], macc[i][j]);
}

__global__ __launch_bounds__(256) void k_scorepass(
    const float* __restrict__ xgT, const int* __restrict__ pidx,
    const float* __restrict__ Wp, const float* __restrict__ bp,
    const float* __restrict__ query,
    float* __restrict__ part_m, float* __restrict__ part_l,
    float* __restrict__ part_ctx)
{
    __shared__ __align__(16) float wp[kG][kE];
    __shared__ __align__(16) float xs[kBT][66];
    __shared__ float bps[kE];

    const int tid  = threadIdx.x;
    int p0, b0;
    decode_swz64(blockIdx.x, p0, b0);
    const int pg   = p0 / kPPG;
    const int eq   = tid & 31;
    const int e0   = eq * 4;
    const int bq8  = (tid >> 5) * 8;
    const int lane = tid & 63;
    const int wv   = tid >> 6;
    const float rsqE = 0.08838834764831845f;

    float qreg[8][4];
#pragma unroll
    for (int i = 0; i < 8; ++i) {
        const float4 qv = *(const float4*)&query[(size_t)(b0 + bq8 + i) * kE + e0];
        qreg[i][0] = qv.x; qreg[i][1] = qv.y; qreg[i][2] = qv.z; qreg[i][3] = qv.w;
    }

    float m[8], l[8], ctx[8][4];
#pragma unroll
    for (int i = 0; i < 8; ++i) {
        m[i] = -1e30f; l[i] = 0.f;
#pragma unroll
        for (int j = 0; j < 4; ++j) ctx[i][j] = 0.f;
    }

    for (int pp = 0; pp < kPPG; ++pp) {
        const int p = p0 + pp;
        const float4* wsrc = (const float4*)(Wp + (size_t)p * kG * kE);
        float4* wdst = (float4*)(&wp[0][0]);
#pragma unroll
        for (int it = 0; it < 8; ++it) wdst[it * 256 + tid] = wsrc[it * 256 + tid];
        if (tid < kE) bps[tid] = bp[p * kE + tid];
#pragma unroll
        for (int t = 0; t < 8; ++t) {
            const int gp = wv + 4 * t;
            const int c0 = pidx[p * kG + 2 * gp];
            const int c1 = pidx[p * kG + 2 * gp + 1];
            const float v0 = xgT[(size_t)c0 * kB + b0 + lane];
            const float v1 = xgT[(size_t)c1 * kB + b0 + lane];
            *(float2*)&xs[lane][2 * gp] = make_float2(v0, v1);
        }
        __syncthreads();

        float bpr[4];
#pragma unroll
        for (int j = 0; j < 4; ++j) bpr[j] = bps[e0 + j];

        float acc[8][4];
#pragma unroll
        for (int i = 0; i < 8; ++i)
#pragma unroll
            for (int j = 0; j < 4; ++j) acc[i][j] = 0.f;

#pragma unroll 4
        for (int gq = 0; gq < 16; ++gq) {
            const int g0 = gq * 4;
            float4 wrow[4];
#pragma unroll
            for (int k = 0; k < 4; ++k) wrow[k] = *(const float4*)&wp[g0 + k][e0];
#pragma unroll
            for (int i = 0; i < 8; ++i) {
                const float2 xa01 = *(const float2*)&xs[bq8 + i][g0];
                const float2 xa23 = *(const float2*)&xs[bq8 + i][g0 + 2];
                const float xa[4] = {xa01.x, xa01.y, xa23.x, xa23.y};
#pragma unroll
                for (int k = 0; k < 4; ++k) {
                    acc[i][0] = fmaf(xa[k], wrow[k].x, acc[i][0]);
                    acc[i][1] = fmaf(xa[k], wrow[k].y, acc[i][1]);
                    acc[i][2] = fmaf(xa[k], wrow[k].z, acc[i][2]);
                    acc[i][3] = fmaf(xa[k], wrow[k].w, acc[i][3]);
                }
            }
        }
#pragma unroll
        for (int i = 0; i < 8; ++i) {
#pragma unroll
            for (int j = 0; j < 4; ++j) acc[i][j] = fmaxf(acc[i][j] + bpr[j], 0.f);
            float ps = acc[i][0] * qreg[i][0] + acc[i][1] * qreg[i][1]
                     + acc[i][2] * qreg[i][2] + acc[i][3] * qreg[i][3];
            ps += __shfl_xor(ps, 1);
            ps += __shfl_xor(ps, 2);
            ps += __shfl_xor(ps, 4);
            ps += __shfl_xor(ps, 8);
            ps += __shfl_xor(ps, 16);
            const float s  = ps * rsqE;
            const float mn = fmaxf(m[i], s);
            const float sc = __expf(m[i] - mn);
            const float w  = __expf(s - mn);
            l[i] = l[i] * sc + w;
#pragma unroll
            for (int j = 0; j < 4; ++j) ctx[i][j] = ctx[i][j] * sc + w * acc[i][j];
            m[i] = mn;
        }
        __syncthreads();
    }

    if (eq == 0) {
#pragma unroll
        for (int i = 0; i < 8; ++i) {
            part_m[(size_t)(b0 + bq8 + i) * kNPG + pg] = m[i];
            part_l[(size_t)(b0 + bq8 + i) * kNPG + pg] = l[i];
        }
    }
#pragma unroll
    for (int i = 0; i < 8; ++i)
#pragma unroll
        for (int j = 0; j < 4; ++j)
            part_ctx[((size_t)(b0 + bq8 + i) * kNPG + pg) * kE + e0 + j] = ctx[i][j];
}

// ---------------------------------------------------------------------------
// Shared small kernels
// ---------------------------------------------------------------------------
__global__ __launch_bounds__(128) void k_query2(
    const int* __restrict__ x_tissue, const float* __restrict__ tissue_emb,
    const float* __restrict__ pmean, const float* __restrict__ Wq,
    const float* __restrict__ bqv, float* __restrict__ query)
{
    __shared__ float comb[2 * kE];
    const int b = blockIdx.x, tid = threadIdx.x;
    const int t = x_tissue[b];
    comb[tid] = tissue_emb[t * kE + tid];
    float ms = 0.f;
#pragma unroll 8
    for (int g = 0; g < kNPG; ++g)
        ms += pmean[((size_t)g * kB + b) * kE + tid];
    comb[kE + tid] = ms * (1.0f / (float)kP);
    __syncthreads();
    float a = bqv[tid];
#pragma unroll 8
    for (int k = 0; k < 2 * kE; ++k) a = fmaf(comb[k], Wq[k * kE + tid], a);
    query[(size_t)b * kE + tid] = fmaxf(a, 0.f);
}

__global__ __launch_bounds__(128) void k_query(
    const int* __restrict__ x_tissue, const float* __restrict__ tissue_emb,
    const float* __restrict__ meanSum, const float* __restrict__ Wq,
    const float* __restrict__ bqv, float* __restrict__ query)
{
    __shared__ float comb[2 * kE];
    const int b = blockIdx.x, tid = threadIdx.x;
    const int t = x_tissue[b];
    comb[tid] = tissue_emb[t * kE + tid];
    comb[kE + tid] = meanSum[(size_t)b * kE + tid] * (1.0f / (float)kP);
    __syncthreads();
    float a = bqv[tid];
#pragma unroll 8
    for (int k = 0; k < 2 * kE; ++k) a = fmaf(comb[k], Wq[k * kE + tid], a);
    query[(size_t)b * kE + tid] = fmaxf(a, 0.f);
}

// fused merge + qkv: context computed once, kept in LDS for the qkv GEMV
__global__ __launch_bounds__(128) void k_mergeqkv(
    const float* __restrict__ part_m, const float* __restrict__ part_l,
    const float* __restrict__ part_ctx, const float* __restrict__ Wqkv,
    const float* __restrict__ bqkv, float* __restrict__ context,
    float* __restrict__ qkv)
{
    __shared__ float cs[kE];
    const int b = blockIdx.x, e = threadIdx.x;
    float M = -1e30f;
#pragma unroll
    for (int g = 0; g < kNPG; ++g) M = fmaxf(M, part_m[(size_t)b * kNPG + g]);
    float L = 0.f, cx = 0.f;
#pragma unroll
    for (int g = 0; g < kNPG; ++g) {
        const float w = __expf(part_m[(size_t)b * kNPG + g] - M);
        L  += part_l[(size_t)b * kNPG + g] * w;
        cx += w * part_ctx[((size_t)b * kNPG + g) * kE + e];
    }
    const float c = cx / L;
    context[(size_t)b * kE + e] = c;
    cs[e] = c;
    __syncthreads();
#pragma unroll
    for (int part = 0; part < 3; ++part) {
        const int col = part * kE + e;
        float a = bqkv[col];
#pragma unroll 8
        for (int k = 0; k < kE; ++k) a = fmaf(cs[k], Wqkv[k * 3 * kE + col], a);
        qkv[(size_t)b * 3 * kE + col] = a;
    }
}

// parallel deterministic tissue-group build (R8-proven)
__global__ __launch_bounds__(256) void k_groups2(
    const int* __restrict__ x_tissue, int* __restrict__ gstart,
    int* __restrict__ glist)
{
    __shared__ int cnts[kT];
    __shared__ int starts[kT + 1];
    __shared__ int wtot[4];
    __shared__ int running;
    const int tid = threadIdx.x;
    const int t   = blockIdx.x;
    const int lane = tid & 63;
    const int wid  = tid >> 6;

    if (tid < kT) cnts[tid] = 0;
    __syncthreads();
    for (int i = tid; i < kB; i += 256) atomicAdd(&cnts[x_tissue[i]], 1);
    __syncthreads();
    if (tid == 0) {
        int a = 0;
        for (int t2 = 0; t2 < kT; ++t2) { starts[t2] = a; a += cnts[t2]; }
        starts[kT] = a;
        running = starts[t];
    }
    __syncthreads();
    if (t == 0 && tid <= kT) gstart[tid] = starts[tid];

    for (int c = 0; c < kB; c += 256) {
        const int idx = c + tid;
        const bool flag = (x_tissue[idx] == t);
        const unsigned long long mask = __ballot(flag);
        const int rank = __popcll(mask & ((1ULL << lane) - 1ULL));
        if (lane == 0) wtot[wid] = __popcll(mask);
        __syncthreads();
        int woff = 0;
#pragma unroll
        for (int wj = 0; wj < 4; ++wj) woff += (wj < wid) ? wtot[wj] : 0;
        if (flag) glist[running + woff + rank] = idx;
        __syncthreads();
        if (tid == 0) running += wtot[0] + wtot[1] + wtot[2] + wtot[3];
        __syncthreads();
    }
}

// ---------------------------------------------------------------------------
// k_final: grouped attention (2 members per wave iteration) + Wo + LN-mix
// + MLP + normalize. grid kB, 256 threads.
// ---------------------------------------------------------------------------
__global__ __launch_bounds__(256) void k_final(
    const int* __restrict__ x_tissue, const int* __restrict__ gstart,
    const int* __restrict__ glist, const float* __restrict__ qkv,
    const float* __restrict__ context, const float* __restrict__ Wo,
    const float* __restrict__ bo, const float* __restrict__ ln_g,
    const float* __restrict__ ln_b, const float* __restrict__ W1,
    const float* __restrict__ b1, const float* __restrict__ W2,
    const float* __restrict__ b2, float* __restrict__ out)
{
    __shared__ float qb[kE], att[kE], ctxb[kE], cf[kE], h1s[32];
    __shared__ float rsum[4], rsq[4];
    const int b = blockIdx.x, tid = threadIdx.x;
    const int t = x_tissue[b];
    const int s0 = gstart[t], s1 = gstart[t + 1];
    const int cnt = s1 - s0;
    if (tid < kE) {
        qb[tid]   = qkv[(size_t)b * 3 * kE + tid];
        ctxb[tid] = context[(size_t)b * kE + tid];
    }
    __syncthreads();

    const int h    = tid >> 6;
    const int lane = tid & 63;
    const int d    = lane & 31;
    const int half = lane >> 5;
    const float qd = qb[h * 32 + d];
    const float NEG_INF = -__int_as_float(0x7f800000);

    float m = -1e30f, l = 0.f, o = 0.f;
    for (int j = 0; j < cnt; j += 2) {
        const int jj  = j + half;
        const bool act = (jj < cnt);
        const int c = glist[s0 + (act ? jj : 0)];
        float s = qd * qkv[(size_t)c * 3 * kE + kE + h * 32 + d];
        s += __shfl_xor(s, 1);
        s += __shfl_xor(s, 2);
        s += __shfl_xor(s, 4);
        s += __shfl_xor(s, 8);
        s += __shfl_xor(s, 16);
        s = act ? s * 0.17677669529663687f : NEG_INF;
        const float mn = fmaxf(m, s);
        const float sc = __expf(m - mn);
        const float w  = __expf(s - mn);
        const float vd = qkv[(size_t)c * 3 * kE + 2 * kE + h * 32 + d];
        l = l * sc + w;
        o = o * sc + w * vd;
        m = mn;
    }
    const float m2 = __shfl_xor(m, 32);
    const float l2 = __shfl_xor(l, 32);
    const float o2 = __shfl_xor(o, 32);
    const float mm = fmaxf(m, m2);
    const float wa = __expf(m - mm);
    const float wb = __expf(m2 - mm);
    const float lt = l * wa + l2 * wb;
    const float ot = o * wa + o2 * wb;
    if (lane < 32) att[h * 32 + d] = ot / lt;
    __syncthreads();

    float x = 0.f;
    if (tid < kE) {
        float a = bo[tid];
#pragma unroll 8
        for (int k = 0; k < kE; ++k) a = fmaf(att[k], Wo[k * kE + tid], a);
        x = 0.3f * a + 0.7f * ctxb[tid];
    }
    float sum = (tid < kE) ? x : 0.f;
    float sq  = (tid < kE) ? x * x : 0.f;
#pragma unroll
    for (int off = 1; off <= 32; off <<= 1) {
        sum += __shfl_xor(sum, off);
        sq  += __shfl_xor(sq, off);
    }
    if (lane == 0) { rsum[h] = sum; rsq[h] = sq; }
    __syncthreads();
    const float mu  = (rsum[0] + rsum[1] + rsum[2] + rsum[3]) * (1.0f / kE);
    const float var = (rsq[0] + rsq[1] + rsq[2] + rsq[3]) * (1.0f / kE) - mu * mu;
    if (tid < kE) {
        const float y = (x - mu) * rsqrtf(var + 1e-5f) * ln_g[tid] + ln_b[tid];
        cf[tid] = (cnt > 1) ? y : ctxb[tid];
    }
    __syncthreads();
    if (tid < 32) {
        float a = b1[tid];
#pragma unroll 8
        for (int e = 0; e < kE; ++e) a = fmaf(cf[e], W1[e * 32 + tid], a);
        h1s[tid] = fmaxf(a, 0.f);
    }
    __syncthreads();
    if (tid == 0) {
        float l0 = b2[0], l1 = b2[1];
#pragma unroll
        for (int j = 0; j < 32; ++j) {
            l0 = fmaf(h1s[j], W2[2 * j + 0], l0);
            l1 = fmaf(h1s[j], W2[2 * j + 1], l1);
        }
        const float nrm = sqrtf(l0 * l0 + l1 * l1);
        const float inv = 1.f / fmaxf(nrm, 1e-12f);
        out[2 * b + 0] = l0 * inv;
        out[2 * b + 1] = l1 * inv;
    }
}

// ---------------------------------------------------------------------------
extern "C" void kernel_launch(void* const* d_in, const int* in_sizes, int n_in,
                              void* d_out, int out_size, void* d_ws, size_t ws_size,
                              hipStream_t stream) {
    const float* x_genes    = (const float*)d_in[0];
    const int*   x_tissue   = (const int*)d_in[1];
    const int*   pathway_idx= (const int*)d_in[2];
    const float* Wp         = (const float*)d_in[3];
    const float* bp         = (const float*)d_in[4];
    const float* tissue_emb = (const float*)d_in[5];
    const float* Wq         = (const float*)d_in[6];
    const float* bqv        = (const float*)d_in[7];
    const float* Wqkv       = (const float*)d_in[8];
    const float* bqkv       = (const float*)d_in[9];
    const float* Wo         = (const float*)d_in[10];
    const float* bo         = (const float*)d_in[11];
    const float* ln_g       = (const float*)d_in[12];
    const float* ln_b       = (const float*)d_in[13];
    const float* W1         = (const float*)d_in[14];
    const float* b1         = (const float*)d_in[15];
    const float* W2         = (const float*)d_in[16];
    const float* b2         = (const float*)d_in[17];
    float* out = (float*)d_out;

    char* w = (char*)d_ws;
    size_t off = 0;
    auto carve = [&](size_t bytes) -> void* {
        void* p = (void*)(w + off);
        off += (bytes + 255) & ~(size_t)255;
        return p;
    };
    float* meanSum  = (float*)carve((size_t)kB * kE * 4);
    float* query    = (float*)carve((size_t)kB * kE * 4);
    float* part_m   = (float*)carve((size_t)kB * kNPG * 4);
    float* part_l   = (float*)carve((size_t)kB * kNPG * 4);
    float* part_ctx = (float*)carve((size_t)kB * kNPG * kE * 4);
    float* context  = (float*)carve((size_t)kB * kE * 4);
    float* qkv      = (float*)carve((size_t)kB * 3 * kE * 4);
    int*   gstart   = (int*)carve(256);
    int*   glist    = (int*)carve((size_t)kB * 4);
    float* xgT      = (float*)carve((size_t)kNG * kB * 4);       // 164 MB
    float* pmean    = (float*)carve((size_t)kNPG * kB * kE * 4); // 32 MB
    float* tok      = (float*)carve((size_t)kP * kB * kE * 4);   // 268 MB
    const bool fastTok = (off <= ws_size);

    if (fastTok) {
        dim3 gridTr((kNG + 63) / 64, kB / 64);
        k_transpose<<<gridTr, 256, 0, stream>>>(x_genes, xgT);
        k_tokens<<<kNBT * kNPG, 256, 0, stream>>>(xgT, pathway_idx, Wp, bp, tok, pmean);
        k_query2<<<kB, 128, 0, stream>>>(x_tissue, tissue_emb, pmean, Wq, bqv, query);
        dim3 gridSc(kNBT, kNPG);
        k_scoretok<<<gridSc, 256, 0, stream>>>(tok, query, part_m, part_l, part_ctx);
    } else {
        hipMemsetAsync(meanSum, 0, (size_t)kB * kE * sizeof(float), stream);
        dim3 gridTr((kNG + 63) / 64, kB / 64);
        k_transpose<<<gridTr, 256, 0, stream>>>(x_genes, xgT);
        k_meanpass<<<kNBT * kNPG, 256, 0, stream>>>(xgT, pathway_idx, Wp, bp, meanSum);
        k_query<<<kB, 128, 0, stream>>>(x_tissue, tissue_emb, meanSum, Wq, bqv, query);
        k_scorepass<<<kNBT * kNPG, 256, 0, stream>>>(xgT, pathway_idx, Wp, bp, query,
                                                     part_m, part_l, part_ctx);
    }
    k_mergeqkv<<<kB, 128, 0, stream>>>(part_m, part_l, part_ctx, Wqkv, bqkv,
                                       context, qkv);
    k_groups2<<<kT, 256, 0, stream>>>(x_tissue, gstart, glist);
    k_final<<<kB, 256, 0, stream>>>(x_tissue, gstart, glist, qkv, context,
                                    Wo, bo, ln_g, ln_b, W1, b1, W2, b2, out);
}

// Round 15
// 384.033 us; speedup vs baseline: 1.0025x; 1.0025x over previous
//
#include <hip/hip_runtime.h>
#include <math.h>

// Problem constants
constexpr int kB  = 2048;
constexpr int kNG = 20000;
constexpr int kP  = 256;
constexpr int kG  = 64;
constexpr int kE  = 128;
constexpr int kT  = 32;
constexpr int kNPG = 32;   // number of pathway groups
constexpr int kPPG = 8;    // pathways per group
constexpr int kBT  = 64;   // batch tile
constexpr int kNBT = kB / kBT;   // 32

// ---------------------------------------------------------------------------
// T0: transpose x_genes [B][NG] f32 -> xgT [NG][B] f32 (exact).
// float4 global loads/stores; LDS hops scalar at stride 65 (2-way = free).
// ---------------------------------------------------------------------------
__global__ __launch_bounds__(256) void k_transpose(
    const float* __restrict__ xg, float* __restrict__ xgT)
{
    __shared__ float t[64][65];
    const int g0 = blockIdx.x * 64, b0 = blockIdx.y * 64;
    const int tid = threadIdx.x;
    const bool tail = (g0 + 64 > kNG);

    const int gi = tid & 15;   // float4 column index
    const int br = tid >> 4;   // base row
#pragma unroll
    for (int it = 0; it < 4; ++it) {
        const int b = br + 16 * it;
        const int g = g0 + gi * 4;
        float4 v;
        if (!tail) {
            v = *(const float4*)&xg[(size_t)(b0 + b) * kNG + g];
        } else {
            v.x = (g + 0 < kNG) ? xg[(size_t)(b0 + b) * kNG + g + 0] : 0.f;
            v.y = (g + 1 < kNG) ? xg[(size_t)(b0 + b) * kNG + g + 1] : 0.f;
            v.z = (g + 2 < kNG) ? xg[(size_t)(b0 + b) * kNG + g + 2] : 0.f;
            v.w = (g + 3 < kNG) ? xg[(size_t)(b0 + b) * kNG + g + 3] : 0.f;
        }
        t[b][gi * 4 + 0] = v.x;
        t[b][gi * 4 + 1] = v.y;
        t[b][gi * 4 + 2] = v.z;
        t[b][gi * 4 + 3] = v.w;
    }
    __syncthreads();
    const int bi = tid & 15;
    const int gr = tid >> 4;
#pragma unroll
    for (int it = 0; it < 4; ++it) {
        const int g = gr + 16 * it;
        if (g0 + g < kNG) {
            float4 v;
            v.x = t[4 * bi + 0][g];
            v.y = t[4 * bi + 1][g];
            v.z = t[4 * bi + 2][g];
            v.w = t[4 * bi + 3][g];
            *(float4*)&xgT[(size_t)(g0 + g) * kB + b0 + 4 * bi] = v;
        }
    }
}

// XCD-aware flat-grid decode: 1024 blocks, 8 XCDs
static __device__ __forceinline__ void decode_swz64(int bid, int& p0, int& b0) {
    const int swz = ((bid & 7) << 7) | (bid >> 3);  // bijective, 1024%8==0
    p0 = (swz >> 5) * kPPG;
    b0 = (swz & 31) * kBT;
}

// ---------------------------------------------------------------------------
// k_tokens: R11/R13-proven version (172 us, 0 conflicts, VALUBusy 46%).
// 1024 blocks x 256 threads, 8x4 tile, half-K Wp staging (16 KB).
// LDS 33 KB -> 4 blocks/CU; grid 1024 = 4 x 256 CUs, zero tail.
// Five restructure attempts (reg-prefetch, no-LDS-Wp, 8x8 x2, T14 split)
// all regressed; this shape is the empirical optimum for this GEMM.
// ---------------------------------------------------------------------------
__global__ __launch_bounds__(256) void k_tokens(
    const float* __restrict__ xgT, const int* __restrict__ pidx,
    const float* __restrict__ Wp, const float* __restrict__ bp,
    float* __restrict__ tok, float* __restrict__ pmean)
{
    __shared__ __align__(16) float wp[kG / 2][kE];  // 16 KB (half-K chunk)
    __shared__ __align__(16) float xs[kBT][66];     // 16.5 KB

    const int tid  = threadIdx.x;
    int p0, b0;
    decode_swz64(blockIdx.x, p0, b0);
    const int pg   = p0 / kPPG;
    const int e0   = (tid & 31) * 4;
    const int bq8  = (tid >> 5) * 8;
    const int lane = tid & 63;
    const int wv   = tid >> 6;

    float macc[8][4];
#pragma unroll
    for (int i = 0; i < 8; ++i)
#pragma unroll
        for (int j = 0; j < 4; ++j) macc[i][j] = 0.f;

    for (int pp = 0; pp < kPPG; ++pp) {
        const int p = p0 + pp;
        // stage gathered x tile (coalesced 256B per gene column)
#pragma unroll
        for (int t = 0; t < 8; ++t) {
            const int gp = wv + 4 * t;
            const int c0 = pidx[p * kG + 2 * gp];
            const int c1 = pidx[p * kG + 2 * gp + 1];
            const float v0 = xgT[(size_t)c0 * kB + b0 + lane];
            const float v1 = xgT[(size_t)c1 * kB + b0 + lane];
            *(float2*)&xs[lane][2 * gp] = make_float2(v0, v1);
        }
        // stage Wp half A (genes 0..31): 1024 float4 / 256 thr
        {
            const float4* wsrc = (const float4*)(Wp + (size_t)p * kG * kE);
            float4* wdst = (float4*)(&wp[0][0]);
#pragma unroll
            for (int it = 0; it < 4; ++it) wdst[it * 256 + tid] = wsrc[it * 256 + tid];
        }
        float bpr[4];
        {
            const float4 b4 = *(const float4*)&bp[p * kE + e0];
            bpr[0] = b4.x; bpr[1] = b4.y; bpr[2] = b4.z; bpr[3] = b4.w;
        }
        __syncthreads();

        float acc[8][4];
#pragma unroll
        for (int i = 0; i < 8; ++i)
#pragma unroll
            for (int j = 0; j < 4; ++j) acc[i][j] = 0.f;

#pragma unroll
        for (int half = 0; half < 2; ++half) {
            if (half == 1) {
                __syncthreads();  // all reads of half A done
                const float4* wsrc = (const float4*)(Wp + (size_t)p * kG * kE) + 1024;
                float4* wdst = (float4*)(&wp[0][0]);
#pragma unroll
                for (int it = 0; it < 4; ++it) wdst[it * 256 + tid] = wsrc[it * 256 + tid];
                __syncthreads();  // half B staged
            }
            const int xoff = half * 32;
#pragma unroll 4
            for (int gq = 0; gq < 8; ++gq) {
                const int g0 = gq * 4;
                float4 wrow[4];
#pragma unroll
                for (int k = 0; k < 4; ++k) wrow[k] = *(const float4*)&wp[g0 + k][e0];
#pragma unroll
                for (int i = 0; i < 8; ++i) {
                    const float2 xa01 = *(const float2*)&xs[bq8 + i][xoff + g0];
                    const float2 xa23 = *(const float2*)&xs[bq8 + i][xoff + g0 + 2];
                    const float xa[4] = {xa01.x, xa01.y, xa23.x, xa23.y};
#pragma unroll
                    for (int k = 0; k < 4; ++k) {
                        acc[i][0] = fmaf(xa[k], wrow[k].x, acc[i][0]);
                        acc[i][1] = fmaf(xa[k], wrow[k].y, acc[i][1]);
                        acc[i][2] = fmaf(xa[k], wrow[k].z, acc[i][2]);
                        acc[i][3] = fmaf(xa[k], wrow[k].w, acc[i][3]);
                    }
                }
            }
        }
        // relu + bias, store tokens, accumulate partial mean
#pragma unroll
        for (int i = 0; i < 8; ++i) {
            float4 r4;
            r4.x = fmaxf(acc[i][0] + bpr[0], 0.f);
            r4.y = fmaxf(acc[i][1] + bpr[1], 0.f);
            r4.z = fmaxf(acc[i][2] + bpr[2], 0.f);
            r4.w = fmaxf(acc[i][3] + bpr[3], 0.f);
            macc[i][0] += r4.x; macc[i][1] += r4.y;
            macc[i][2] += r4.z; macc[i][3] += r4.w;
            *(float4*)&tok[((size_t)p * kB + b0 + bq8 + i) * kE + e0] = r4;
        }
        __syncthreads();  // guard xs/wp overwrite next pathway
    }
    // non-atomic partial mean: (pg, b, e) owned by exactly one thread
#pragma unroll
    for (int i = 0; i < 8; ++i)
        *(float4*)&pmean[((size_t)pg * kB + b0 + bq8 + i) * kE + e0] =
            make_float4(macc[i][0], macc[i][1], macc[i][2], macc[i][3]);
}

// ---------------------------------------------------------------------------
// k_scoretok: scores + online softmax + partial ctx from stored tokens.
// ---------------------------------------------------------------------------
__global__ __launch_bounds__(256) void k_scoretok(
    const float* __restrict__ tok, const float* __restrict__ query,
    float* __restrict__ part_m, float* __restrict__ part_l,
    float* __restrict__ part_ctx)
{
    const int tid = threadIdx.x;
    const int b0  = blockIdx.x * kBT;
    const int pg  = blockIdx.y;
    const int eq  = tid & 31;
    const int e0  = eq * 4;
    const int bq8 = (tid >> 5) * 8;
    const float rsqE = 0.08838834764831845f; // 1/sqrt(128)

    float qreg[8][4];
#pragma unroll
    for (int i = 0; i < 8; ++i) {
        const float4 qv = *(const float4*)&query[(size_t)(b0 + bq8 + i) * kE + e0];
        qreg[i][0] = qv.x; qreg[i][1] = qv.y; qreg[i][2] = qv.z; qreg[i][3] = qv.w;
    }

    float m[8], l[8], ctx[8][4];
#pragma unroll
    for (int i = 0; i < 8; ++i) {
        m[i] = -1e30f; l[i] = 0.f;
#pragma unroll
        for (int j = 0; j < 4; ++j) ctx[i][j] = 0.f;
    }

    for (int pp = 0; pp < kPPG; ++pp) {
        const int p = pg * kPPG + pp;
#pragma unroll
        for (int i = 0; i < 8; ++i) {
            const float4 t4 = *(const float4*)&tok[((size_t)p * kB + b0 + bq8 + i) * kE + e0];
            float ps = t4.x * qreg[i][0] + t4.y * qreg[i][1]
                     + t4.z * qreg[i][2] + t4.w * qreg[i][3];
            ps += __shfl_xor(ps, 1);
            ps += __shfl_xor(ps, 2);
            ps += __shfl_xor(ps, 4);
            ps += __shfl_xor(ps, 8);
            ps += __shfl_xor(ps, 16);
            const float s  = ps * rsqE;
            const float mn = fmaxf(m[i], s);
            const float sc = __expf(m[i] - mn);
            const float w  = __expf(s - mn);
            l[i] = l[i] * sc + w;
            ctx[i][0] = ctx[i][0] * sc + w * t4.x;
            ctx[i][1] = ctx[i][1] * sc + w * t4.y;
            ctx[i][2] = ctx[i][2] * sc + w * t4.z;
            ctx[i][3] = ctx[i][3] * sc + w * t4.w;
            m[i] = mn;
        }
    }

    if (eq == 0) {
#pragma unroll
        for (int i = 0; i < 8; ++i) {
            part_m[(size_t)(b0 + bq8 + i) * kNPG + pg] = m[i];
            part_l[(size_t)(b0 + bq8 + i) * kNPG + pg] = l[i];
        }
    }
#pragma unroll
    for (int i = 0; i < 8; ++i)
#pragma unroll
        for (int j = 0; j < 4; ++j)
            part_ctx[((size_t)(b0 + bq8 + i) * kNPG + pg) * kE + e0 + j] = ctx[i][j];
}

// ---------------------------------------------------------------------------
// Fallback pass A/B (R7-proven BT=64 recompute path) — used if tok doesn't fit
// ---------------------------------------------------------------------------
__global__ __launch_bounds__(256) void k_meanpass(
    const float* __restrict__ xgT, const int* __restrict__ pidx,
    const float* __restrict__ Wp, const float* __restrict__ bp,
    float* __restrict__ meanSum)
{
    __shared__ __align__(16) float wp[kG][kE];
    __shared__ __align__(16) float xs[kBT][66];
    __shared__ float bps[kE];

    const int tid  = threadIdx.x;
    int p0, b0;
    decode_swz64(blockIdx.x, p0, b0);
    const int e0   = (tid & 31) * 4;
    const int bq8  = (tid >> 5) * 8;
    const int lane = tid & 63;
    const int wv   = tid >> 6;

    float macc[8][4];
#pragma unroll
    for (int i = 0; i < 8; ++i)
#pragma unroll
        for (int j = 0; j < 4; ++j) macc[i][j] = 0.f;

    for (int pp = 0; pp < kPPG; ++pp) {
        const int p = p0 + pp;
        const float4* wsrc = (const float4*)(Wp + (size_t)p * kG * kE);
        float4* wdst = (float4*)(&wp[0][0]);
#pragma unroll
        for (int it = 0; it < 8; ++it) wdst[it * 256 + tid] = wsrc[it * 256 + tid];
        if (tid < kE) bps[tid] = bp[p * kE + tid];
#pragma unroll
        for (int t = 0; t < 8; ++t) {
            const int gp = wv + 4 * t;
            const int c0 = pidx[p * kG + 2 * gp];
            const int c1 = pidx[p * kG + 2 * gp + 1];
            const float v0 = xgT[(size_t)c0 * kB + b0 + lane];
            const float v1 = xgT[(size_t)c1 * kB + b0 + lane];
            *(float2*)&xs[lane][2 * gp] = make_float2(v0, v1);
        }
        __syncthreads();

        float bpr[4];
#pragma unroll
        for (int j = 0; j < 4; ++j) bpr[j] = bps[e0 + j];

        float acc[8][4];
#pragma unroll
        for (int i = 0; i < 8; ++i)
#pragma unroll
            for (int j = 0; j < 4; ++j) acc[i][j] = 0.f;

#pragma unroll 4
        for (int gq = 0; gq < 16; ++gq) {
            const int g0 = gq * 4;
            float4 wrow[4];
#pragma unroll
            for (int k = 0; k < 4; ++k) wrow[k] = *(const float4*)&wp[g0 + k][e0];
#pragma unroll
            for (int i = 0; i < 8; ++i) {
                const float2 xa01 = *(const float2*)&xs[bq8 + i][g0];
                const float2 xa23 = *(const float2*)&xs[bq8 + i][g0 + 2];
                const float xa[4] = {xa01.x, xa01.y, xa23.x, xa23.y};
#pragma unroll
                for (int k = 0; k < 4; ++k) {
                    acc[i][0] = fmaf(xa[k], wrow[k].x, acc[i][0]);
                    acc[i][1] = fmaf(xa[k], wrow[k].y, acc[i][1]);
                    acc[i][2] = fmaf(xa[k], wrow[k].z, acc[i][2]);
                    acc[i][3] = fmaf(xa[k], wrow[k].w, acc[i][3]);
                }
            }
        }
#pragma unroll
        for (int i = 0; i < 8; ++i)
#pragma unroll
            for (int j = 0; j < 4; ++j)
                macc[i][j] += fmaxf(acc[i][j] + bpr[j], 0.f);
        __syncthreads();
    }
#pragma unroll
    for (int i = 0; i < 8; ++i)
#pragma unroll
        for (int j = 0; j < 4; ++j)
            atomicAdd(&meanSum[(size_t)(b0 + bq8 + i) * kE + e0 + j], macc[i][j]);
}

__global__ __launch_bounds__(256) void k_scorepass(
    const float* __restrict__ xgT, const int* __restrict__ pidx,
    const float* __restrict__ Wp, const float* __restrict__ bp,
    const float* __restrict__ query,
    float* __restrict__ part_m, float* __restrict__ part_l,
    float* __restrict__ part_ctx)
{
    __shared__ __align__(16) float wp[kG][kE];
    __shared__ __align__(16) float xs[kBT][66];
    __shared__ float bps[kE];

    const int tid  = threadIdx.x;
    int p0, b0;
    decode_swz64(blockIdx.x, p0, b0);
    const int pg   = p0 / kPPG;
    const int eq   = tid & 31;
    const int e0   = eq * 4;
    const int bq8  = (tid >> 5) * 8;
    const int lane = tid & 63;
    const int wv   = tid >> 6;
    const float rsqE = 0.08838834764831845f;

    float qreg[8][4];
#pragma unroll
    for (int i = 0; i < 8; ++i) {
        const float4 qv = *(const float4*)&query[(size_t)(b0 + bq8 + i) * kE + e0];
        qreg[i][0] = qv.x; qreg[i][1] = qv.y; qreg[i][2] = qv.z; qreg[i][3] = qv.w;
    }

    float m[8], l[8], ctx[8][4];
#pragma unroll
    for (int i = 0; i < 8; ++i) {
        m[i] = -1e30f; l[i] = 0.f;
#pragma unroll
        for (int j = 0; j < 4; ++j) ctx[i][j] = 0.f;
    }

    for (int pp = 0; pp < kPPG; ++pp) {
        const int p = p0 + pp;
        const float4* wsrc = (const float4*)(Wp + (size_t)p * kG * kE);
        float4* wdst = (float4*)(&wp[0][0]);
#pragma unroll
        for (int it = 0; it < 8; ++it) wdst[it * 256 + tid] = wsrc[it * 256 + tid];
        if (tid < kE) bps[tid] = bp[p * kE + tid];
#pragma unroll
        for (int t = 0; t < 8; ++t) {
            const int gp = wv + 4 * t;
            const int c0 = pidx[p * kG + 2 * gp];
            const int c1 = pidx[p * kG + 2 * gp + 1];
            const float v0 = xgT[(size_t)c0 * kB + b0 + lane];
            const float v1 = xgT[(size_t)c1 * kB + b0 + lane];
            *(float2*)&xs[lane][2 * gp] = make_float2(v0, v1);
        }
        __syncthreads();

        float bpr[4];
#pragma unroll
        for (int j = 0; j < 4; ++j) bpr[j] = bps[e0 + j];

        float acc[8][4];
#pragma unroll
        for (int i = 0; i < 8; ++i)
#pragma unroll
            for (int j = 0; j < 4; ++j) acc[i][j] = 0.f;

#pragma unroll 4
        for (int gq = 0; gq < 16; ++gq) {
            const int g0 = gq * 4;
            float4 wrow[4];
#pragma unroll
            for (int k = 0; k < 4; ++k) wrow[k] = *(const float4*)&wp[g0 + k][e0];
#pragma unroll
            for (int i = 0; i < 8; ++i) {
                const float2 xa01 = *(const float2*)&xs[bq8 + i][g0];
                const float2 xa23 = *(const float2*)&xs[bq8 + i][g0 + 2];
                const float xa[4] = {xa01.x, xa01.y, xa23.x, xa23.y};
#pragma unroll
                for (int k = 0; k < 4; ++k) {
                    acc[i][0] = fmaf(xa[k], wrow[k].x, acc[i][0]);
                    acc[i][1] = fmaf(xa[k], wrow[k].y, acc[i][1]);
                    acc[i][2] = fmaf(xa[k], wrow[k].z, acc[i][2]);
                    acc[i][3] = fmaf(xa[k], wrow[k].w, acc[i][3]);
                }
            }
        }
#pragma unroll
        for (int i = 0; i < 8; ++i) {
#pragma unroll
            for (int j = 0; j < 4; ++j) acc[i][j] = fmaxf(acc[i][j] + bpr[j], 0.f);
            float ps = acc[i][0] * qreg[i][0] + acc[i][1] * qreg[i][1]
                     + acc[i][2] * qreg[i][2] + acc[i][3] * qreg[i][3];
            ps += __shfl_xor(ps, 1);
            ps += __shfl_xor(ps, 2);
            ps += __shfl_xor(ps, 4);
            ps += __shfl_xor(ps, 8);
            ps += __shfl_xor(ps, 16);
            const float s  = ps * rsqE;
            const float mn = fmaxf(m[i], s);
            const float sc = __expf(m[i] - mn);
            const float w  = __expf(s - mn);
            l[i] = l[i] * sc + w;
#pragma unroll
            for (int j = 0; j < 4; ++j) ctx[i][j] = ctx[i][j] * sc + w * acc[i][j];
            m[i] = mn;
        }
        __syncthreads();
    }

    if (eq == 0) {
#pragma unroll
        for (int i = 0; i < 8; ++i) {
            part_m[(size_t)(b0 + bq8 + i) * kNPG + pg] = m[i];
            part_l[(size_t)(b0 + bq8 + i) * kNPG + pg] = l[i];
        }
    }
#pragma unroll
    for (int i = 0; i < 8; ++i)
#pragma unroll
        for (int j = 0; j < 4; ++j)
            part_ctx[((size_t)(b0 + bq8 + i) * kNPG + pg) * kE + e0 + j] = ctx[i][j];
}

// ---------------------------------------------------------------------------
// Shared small kernels
// ---------------------------------------------------------------------------
__global__ __launch_bounds__(128) void k_query2(
    const int* __restrict__ x_tissue, const float* __restrict__ tissue_emb,
    const float* __restrict__ pmean, const float* __restrict__ Wq,
    const float* __restrict__ bqv, float* __restrict__ query)
{
    __shared__ float comb[2 * kE];
    const int b = blockIdx.x, tid = threadIdx.x;
    const int t = x_tissue[b];
    comb[tid] = tissue_emb[t * kE + tid];
    float ms = 0.f;
#pragma unroll 8
    for (int g = 0; g < kNPG; ++g)
        ms += pmean[((size_t)g * kB + b) * kE + tid];
    comb[kE + tid] = ms * (1.0f / (float)kP);
    __syncthreads();
    float a = bqv[tid];
#pragma unroll 8
    for (int k = 0; k < 2 * kE; ++k) a = fmaf(comb[k], Wq[k * kE + tid], a);
    query[(size_t)b * kE + tid] = fmaxf(a, 0.f);
}

__global__ __launch_bounds__(128) void k_query(
    const int* __restrict__ x_tissue, const float* __restrict__ tissue_emb,
    const float* __restrict__ meanSum, const float* __restrict__ Wq,
    const float* __restrict__ bqv, float* __restrict__ query)
{
    __shared__ float comb[2 * kE];
    const int b = blockIdx.x, tid = threadIdx.x;
    const int t = x_tissue[b];
    comb[tid] = tissue_emb[t * kE + tid];
    comb[kE + tid] = meanSum[(size_t)b * kE + tid] * (1.0f / (float)kP);
    __syncthreads();
    float a = bqv[tid];
#pragma unroll 8
    for (int k = 0; k < 2 * kE; ++k) a = fmaf(comb[k], Wq[k * kE + tid], a);
    query[(size_t)b * kE + tid] = fmaxf(a, 0.f);
}

// fused merge + qkv: context computed once, kept in LDS for the qkv GEMV
__global__ __launch_bounds__(128) void k_mergeqkv(
    const float* __restrict__ part_m, const float* __restrict__ part_l,
    const float* __restrict__ part_ctx, const float* __restrict__ Wqkv,
    const float* __restrict__ bqkv, float* __restrict__ context,
    float* __restrict__ qkv)
{
    __shared__ float cs[kE];
    const int b = blockIdx.x, e = threadIdx.x;
    float M = -1e30f;
#pragma unroll
    for (int g = 0; g < kNPG; ++g) M = fmaxf(M, part_m[(size_t)b * kNPG + g]);
    float L = 0.f, cx = 0.f;
#pragma unroll
    for (int g = 0; g < kNPG; ++g) {
        const float w = __expf(part_m[(size_t)b * kNPG + g] - M);
        L  += part_l[(size_t)b * kNPG + g] * w;
        cx += w * part_ctx[((size_t)b * kNPG + g) * kE + e];
    }
    const float c = cx / L;
    context[(size_t)b * kE + e] = c;
    cs[e] = c;
    __syncthreads();
#pragma unroll
    for (int part = 0; part < 3; ++part) {
        const int col = part * kE + e;
        float a = bqkv[col];
#pragma unroll 8
        for (int k = 0; k < kE; ++k) a = fmaf(cs[k], Wqkv[k * 3 * kE + col], a);
        qkv[(size_t)b * 3 * kE + col] = a;
    }
}

// parallel deterministic tissue-group build (R8-proven)
__global__ __launch_bounds__(256) void k_groups2(
    const int* __restrict__ x_tissue, int* __restrict__ gstart,
    int* __restrict__ glist)
{
    __shared__ int cnts[kT];
    __shared__ int starts[kT + 1];
    __shared__ int wtot[4];
    __shared__ int running;
    const int tid = threadIdx.x;
    const int t   = blockIdx.x;
    const int lane = tid & 63;
    const int wid  = tid >> 6;

    if (tid < kT) cnts[tid] = 0;
    __syncthreads();
    for (int i = tid; i < kB; i += 256) atomicAdd(&cnts[x_tissue[i]], 1);
    __syncthreads();
    if (tid == 0) {
        int a = 0;
        for (int t2 = 0; t2 < kT; ++t2) { starts[t2] = a; a += cnts[t2]; }
        starts[kT] = a;
        running = starts[t];
    }
    __syncthreads();
    if (t == 0 && tid <= kT) gstart[tid] = starts[tid];

    for (int c = 0; c < kB; c += 256) {
        const int idx = c + tid;
        const bool flag = (x_tissue[idx] == t);
        const unsigned long long mask = __ballot(flag);
        const int rank = __popcll(mask & ((1ULL << lane) - 1ULL));
        if (lane == 0) wtot[wid] = __popcll(mask);
        __syncthreads();
        int woff = 0;
#pragma unroll
        for (int wj = 0; wj < 4; ++wj) woff += (wj < wid) ? wtot[wj] : 0;
        if (flag) glist[running + woff + rank] = idx;
        __syncthreads();
        if (tid == 0) running += wtot[0] + wtot[1] + wtot[2] + wtot[3];
        __syncthreads();
    }
}

// ---------------------------------------------------------------------------
// k_final: grouped attention (2 members per wave iteration) + Wo + LN-mix
// + MLP + normalize. grid kB, 256 threads.
// ---------------------------------------------------------------------------
__global__ __launch_bounds__(256) void k_final(
    const int* __restrict__ x_tissue, const int* __restrict__ gstart,
    const int* __restrict__ glist, const float* __restrict__ qkv,
    const float* __restrict__ context, const float* __restrict__ Wo,
    const float* __restrict__ bo, const float* __restrict__ ln_g,
    const float* __restrict__ ln_b, const float* __restrict__ W1,
    const float* __restrict__ b1, const float* __restrict__ W2,
    const float* __restrict__ b2, float* __restrict__ out)
{
    __shared__ float qb[kE], att[kE], ctxb[kE], cf[kE], h1s[32];
    __shared__ float rsum[4], rsq[4];
    const int b = blockIdx.x, tid = threadIdx.x;
    const int t = x_tissue[b];
    const int s0 = gstart[t], s1 = gstart[t + 1];
    const int cnt = s1 - s0;
    if (tid < kE) {
        qb[tid]   = qkv[(size_t)b * 3 * kE + tid];
        ctxb[tid] = context[(size_t)b * kE + tid];
    }
    __syncthreads();

    const int h    = tid >> 6;
    const int lane = tid & 63;
    const int d    = lane & 31;
    const int half = lane >> 5;
    const float qd = qb[h * 32 + d];
    const float NEG_INF = -__int_as_float(0x7f800000);

    float m = -1e30f, l = 0.f, o = 0.f;
    for (int j = 0; j < cnt; j += 2) {
        const int jj  = j + half;
        const bool act = (jj < cnt);
        const int c = glist[s0 + (act ? jj : 0)];
        float s = qd * qkv[(size_t)c * 3 * kE + kE + h * 32 + d];
        s += __shfl_xor(s, 1);
        s += __shfl_xor(s, 2);
        s += __shfl_xor(s, 4);
        s += __shfl_xor(s, 8);
        s += __shfl_xor(s, 16);
        s = act ? s * 0.17677669529663687f : NEG_INF;
        const float mn = fmaxf(m, s);
        const float sc = __expf(m - mn);
        const float w  = __expf(s - mn);
        const float vd = qkv[(size_t)c * 3 * kE + 2 * kE + h * 32 + d];
        l = l * sc + w;
        o = o * sc + w * vd;
        m = mn;
    }
    const float m2 = __shfl_xor(m, 32);
    const float l2 = __shfl_xor(l, 32);
    const float o2 = __shfl_xor(o, 32);
    const float mm = fmaxf(m, m2);
    const float wa = __expf(m - mm);
    const float wb = __expf(m2 - mm);
    const float lt = l * wa + l2 * wb;
    const float ot = o * wa + o2 * wb;
    if (lane < 32) att[h * 32 + d] = ot / lt;
    __syncthreads();

    float x = 0.f;
    if (tid < kE) {
        float a = bo[tid];
#pragma unroll 8
        for (int k = 0; k < kE; ++k) a = fmaf(att[k], Wo[k * kE + tid], a);
        x = 0.3f * a + 0.7f * ctxb[tid];
    }
    float sum = (tid < kE) ? x : 0.f;
    float sq  = (tid < kE) ? x * x : 0.f;
#pragma unroll
    for (int off = 1; off <= 32; off <<= 1) {
        sum += __shfl_xor(sum, off);
        sq  += __shfl_xor(sq, off);
    }
    if (lane == 0) { rsum[h] = sum; rsq[h] = sq; }
    __syncthreads();
    const float mu  = (rsum[0] + rsum[1] + rsum[2] + rsum[3]) * (1.0f / kE);
    const float var = (rsq[0] + rsq[1] + rsq[2] + rsq[3]) * (1.0f / kE) - mu * mu;
    if (tid < kE) {
        const float y = (x - mu) * rsqrtf(var + 1e-5f) * ln_g[tid] + ln_b[tid];
        cf[tid] = (cnt > 1) ? y : ctxb[tid];
    }
    __syncthreads();
    if (tid < 32) {
        float a = b1[tid];
#pragma unroll 8
        for (int e = 0; e < kE; ++e) a = fmaf(cf[e], W1[e * 32 + tid], a);
        h1s[tid] = fmaxf(a, 0.f);
    }
    __syncthreads();
    if (tid == 0) {
        float l0 = b2[0], l1 = b2[1];
#pragma unroll
        for (int j = 0; j < 32; ++j) {
            l0 = fmaf(h1s[j], W2[2 * j + 0], l0);
            l1 = fmaf(h1s[j], W2[2 * j + 1], l1);
        }
        const float nrm = sqrtf(l0 * l0 + l1 * l1);
        const float inv = 1.f / fmaxf(nrm, 1e-12f);
        out[2 * b + 0] = l0 * inv;
        out[2 * b + 1] = l1 * inv;
    }
}

// ---------------------------------------------------------------------------
extern "C" void kernel_launch(void* const* d_in, const int* in_sizes, int n_in,
                              void* d_out, int out_size, void* d_ws, size_t ws_size,
                              hipStream_t stream) {
    const float* x_genes    = (const float*)d_in[0];
    const int*   x_tissue   = (const int*)d_in[1];
    const int*   pathway_idx= (const int*)d_in[2];
    const float* Wp         = (const float*)d_in[3];
    const float* bp         = (const float*)d_in[4];
    const float* tissue_emb = (const float*)d_in[5];
    const float* Wq         = (const float*)d_in[6];
    const float* bqv        = (const float*)d_in[7];
    const float* Wqkv       = (const float*)d_in[8];
    const float* bqkv       = (const float*)d_in[9];
    const float* Wo         = (const float*)d_in[10];
    const float* bo         = (const float*)d_in[11];
    const float* ln_g       = (const float*)d_in[12];
    const float* ln_b       = (const float*)d_in[13];
    const float* W1         = (const float*)d_in[14];
    const float* b1         = (const float*)d_in[15];
    const float* W2         = (const float*)d_in[16];
    const float* b2         = (const float*)d_in[17];
    float* out = (float*)d_out;

    char* w = (char*)d_ws;
    size_t off = 0;
    auto carve = [&](size_t bytes) -> void* {
        void* p = (void*)(w + off);
        off += (bytes + 255) & ~(size_t)255;
        return p;
    };
    float* meanSum  = (float*)carve((size_t)kB * kE * 4);
    float* query    = (float*)carve((size_t)kB * kE * 4);
    float* part_m   = (float*)carve((size_t)kB * kNPG * 4);
    float* part_l   = (float*)carve((size_t)kB * kNPG * 4);
    float* part_ctx = (float*)carve((size_t)kB * kNPG * kE * 4);
    float* context  = (float*)carve((size_t)kB * kE * 4);
    float* qkv      = (float*)carve((size_t)kB * 3 * kE * 4);
    int*   gstart   = (int*)carve(256);
    int*   glist    = (int*)carve((size_t)kB * 4);
    float* xgT      = (float*)carve((size_t)kNG * kB * 4);       // 164 MB
    float* pmean    = (float*)carve((size_t)kNPG * kB * kE * 4); // 32 MB
    float* tok      = (float*)carve((size_t)kP * kB * kE * 4);   // 268 MB
    const bool fastTok = (off <= ws_size);

    if (fastTok) {
        dim3 gridTr((kNG + 63) / 64, kB / 64);
        k_transpose<<<gridTr, 256, 0, stream>>>(x_genes, xgT);
        k_tokens<<<kNBT * kNPG, 256, 0, stream>>>(xgT, pathway_idx, Wp, bp, tok, pmean);
        k_query2<<<kB, 128, 0, stream>>>(x_tissue, tissue_emb, pmean, Wq, bqv, query);
        dim3 gridSc(kNBT, kNPG);
        k_scoretok<<<gridSc, 256, 0, stream>>>(tok, query, part_m, part_l, part_ctx);
    } else {
        hipMemsetAsync(meanSum, 0, (size_t)kB * kE * sizeof(float), stream);
        dim3 gridTr((kNG + 63) / 64, kB / 64);
        k_transpose<<<gridTr, 256, 0, stream>>>(x_genes, xgT);
        k_meanpass<<<kNBT * kNPG, 256, 0, stream>>>(xgT, pathway_idx, Wp, bp, meanSum);
        k_query<<<kB, 128, 0, stream>>>(x_tissue, tissue_emb, meanSum, Wq, bqv, query);
        k_scorepass<<<kNBT * kNPG, 256, 0, stream>>>(xgT, pathway_idx, Wp, bp, query,
                                                     part_m, part_l, part_ctx);
    }
    k_mergeqkv<<<kB, 128, 0, stream>>>(part_m, part_l, part_ctx, Wqkv, bqkv,
                                       context, qkv);
    k_groups2<<<kT, 256, 0, stream>>>(x_tissue, gstart, glist);
    k_final<<<kB, 256, 0, stream>>>(x_tissue, gstart, glist, qkv, context,
                                    Wo, bo, ln_g, ln_b, W1, b1, W2, b2, out);
}